// Round 1
// baseline (247.471 us; speedup 1.0000x reference)
//
#include <hip/hip_runtime.h>
#include <math.h>

#define L_TOK 16
#define DMODEL 1024
#define NHEAD 16
#define DHEAD 64
#define NBLK 1024
#define BSZ 16
#define START_POS_C 16368
#define TTOT 16384
#define SPLITS 128
#define CHUNK 128          // tokens per block (4 waves x 32 tokens)
#define KSPLIT 16
#define QSCALE (0.125f * 1.4426950408889634f)   // 1/sqrt(64) * log2(e)

// workspace offsets, in floats (layout unchanged — 12.4 MB proven scale)
#define OFF_QKVP 0                                          // 16*16*3072 = 786432
#define OFF_QW   (OFF_QKVP + KSPLIT * L_TOK * 3 * DMODEL)   // 786432
#define OFF_ACC  (OFF_QW + NHEAD * L_TOK * DHEAD)           // 802816
#define OFF_M    (OFF_ACC + NHEAD * SPLITS * L_TOK * DHEAD) // 2899968
#define OFF_SE   (OFF_M + NHEAD * SPLITS * L_TOK)           // 2932736
#define OFF_ATTN (OFF_SE + NHEAD * SPLITS * L_TOK)          // 2965504
#define OFF_PROJP (OFF_ATTN + L_TOK * DMODEL)               // 2981888

typedef _Float16 half4_t __attribute__((ext_vector_type(4)));
typedef _Float16 half8_t __attribute__((ext_vector_type(8)));
typedef float float4v __attribute__((ext_vector_type(4)));
typedef float float2v __attribute__((ext_vector_type(2)));

union H8 { _Float16 h[8]; half8_t v; };
union H4 { _Float16 h[4]; half4_t v; };

// ---------------------------------------------------------------------------
// Split-K partial GEMM v2: each block covers 512 DISJOINT cols (wave wv owns
// cols [bx*512 + wv*128 + lane*2, +2)) — W read exactly once. All 16 rows of
// x accumulated per thread; x staged transposed in LDS and read via broadcast
// ds_read_b128 (uniform address, conflict-free). grid = (ncols/512, KSPLIT).
// ---------------------------------------------------------------------------
__global__ __launch_bounds__(256) void gemm16(const float* __restrict__ x,
                                              const float* __restrict__ W,
                                              float* __restrict__ part,
                                              int ncols) {
    const int lane = threadIdx.x & 63;
    const int wv = threadIdx.x >> 6;
    const int col = blockIdx.x * 512 + wv * 128 + lane * 2;
    const int k0 = blockIdx.y * (DMODEL / KSPLIT);   // 64 k's per block

    __shared__ __align__(16) float sxT[64 * 16];     // [k][l] transposed slice
#pragma unroll
    for (int i = threadIdx.x; i < 64 * 16; i += 256) {
        int k = i & 63, l = i >> 6;                  // consecutive tid -> consecutive k (coalesced)
        sxT[k * 16 + l] = x[(size_t)l * DMODEL + k0 + k];
    }
    __syncthreads();

    float2v acc[16];
#pragma unroll
    for (int l = 0; l < 16; ++l) acc[l] = (float2v){0.f, 0.f};

#pragma unroll 8
    for (int k = 0; k < 64; ++k) {
        float2v w2 = *(const float2v*)&W[(size_t)(k0 + k) * ncols + col];
        const float4v* xk = (const float4v*)&sxT[k * 16];
        float4v xa = xk[0], xb = xk[1], xc = xk[2], xd = xk[3];
        acc[0]  += w2 * xa[0];  acc[1]  += w2 * xa[1];
        acc[2]  += w2 * xa[2];  acc[3]  += w2 * xa[3];
        acc[4]  += w2 * xb[0];  acc[5]  += w2 * xb[1];
        acc[6]  += w2 * xb[2];  acc[7]  += w2 * xb[3];
        acc[8]  += w2 * xc[0];  acc[9]  += w2 * xc[1];
        acc[10] += w2 * xc[2];  acc[11] += w2 * xc[3];
        acc[12] += w2 * xd[0];  acc[13] += w2 * xd[1];
        acc[14] += w2 * xd[2];  acc[15] += w2 * xd[3];
    }

    const size_t base = ((size_t)blockIdx.y * L_TOK) * ncols + col;
#pragma unroll
    for (int l = 0; l < 16; ++l)
        *(float2v*)&part[base + (size_t)l * ncols] = acc[l];
}

// ---------------------------------------------------------------------------
// Reduce split-K partials of QKV, add bias, scatter (unchanged).
// ---------------------------------------------------------------------------
__global__ __launch_bounds__(256) void qkv_reduce_scatter(const float* __restrict__ part,
                                                          const float* __restrict__ b_attn,
                                                          const int* __restrict__ block_ids,
                                                          float* __restrict__ qws,
                                                          float* __restrict__ kpool,
                                                          float* __restrict__ vpool) {
    int tid = blockIdx.x * 256 + threadIdx.x;
    int n = tid % (3 * DMODEL);
    int l = tid / (3 * DMODEL);
    float s = b_attn[n];
#pragma unroll
    for (int kb = 0; kb < KSPLIT; ++kb)
        s += part[((size_t)kb * L_TOK + l) * (3 * DMODEL) + n];
    int sec = n >> 10;
    int m = n & (DMODEL - 1);
    int h = m >> 6;
    int dd = m & 63;
    if (sec == 0) {
        qws[(h * L_TOK + l) * DHEAD + dd] = s * QSCALE;
    } else {
        int pos = START_POS_C + l;
        int blk = block_ids[pos >> 4];
        int off = pos & 15;
        size_t idx = (((size_t)blk * BSZ + off) * NHEAD + h) * DHEAD + dd;
        if (sec == 1) kpool[idx] = s;
        else          vpool[idx] = s;
    }
}

// ---------------------------------------------------------------------------
// Flash-decode paged attention v6. Same structure as v5, plus a scheduling
// fence after the load section: v5 compiled to VGPR=36, i.e. the allocator
// re-batched the 44 up-front VMEM loads into small latency-serialized groups.
// sched_barrier(0) pins all loads above the compute, keeping ~16KB/wave in
// flight (VGPR ~110, still within the (256,4) cap of 128).
// ---------------------------------------------------------------------------
__global__ __launch_bounds__(256, 4) void paged_attn(const float* __restrict__ kpool,
                                                     const float* __restrict__ vpool,
                                                     const int* __restrict__ block_ids,
                                                     const float* __restrict__ qws,
                                                     float* __restrict__ accws,
                                                     float* __restrict__ m_arr,
                                                     float* __restrict__ se_arr) {
    const int h = blockIdx.x;
    const int s = blockIdx.y;
    const int tid = threadIdx.x;
    const int w = tid >> 6;
    const int lane = tid & 63;
    const int c = lane & 15;
    const int quad = lane >> 4;

    __shared__ __align__(16) float sacc[4][16][68];   // stride 68: 2-way banks, 16B rows
    __shared__ float sm[4][16], sse[4][16];

    const int pb0 = block_ids[s * 8 + 2 * w];
    const int pb1 = block_ids[s * 8 + 2 * w + 1];
    const int tb0 = s * CHUNK + w * 32;
    const int tb1 = tb0 + 16;

    // ---- issue ALL global loads up front ----
    const float* qr = qws + ((size_t)(h * L_TOK + c)) * DHEAD + quad * 8;
    float4 q0 = *(const float4*)(qr);
    float4 q1 = *(const float4*)(qr + 4);
    float4 q2 = *(const float4*)(qr + 32);
    float4 q3 = *(const float4*)(qr + 36);
    const float* kr0 = kpool + (((size_t)pb0 * BSZ + c) * NHEAD + h) * DHEAD + quad * 8;
    const float* kr1 = kpool + (((size_t)pb1 * BSZ + c) * NHEAD + h) * DHEAD + quad * 8;
    float4 k0a = *(const float4*)(kr0);      float4 k0b = *(const float4*)(kr0 + 4);
    float4 k0c = *(const float4*)(kr0 + 32); float4 k0d = *(const float4*)(kr0 + 36);
    float4 k1a = *(const float4*)(kr1);      float4 k1b = *(const float4*)(kr1 + 4);
    float4 k1c = *(const float4*)(kr1 + 32); float4 k1d = *(const float4*)(kr1 + 36);
    // V gathered in PV B-frag layout: v[tile][j][ndv] = V[4*quad+j][16*ndv+c]
    float v0[4][4], v1[4][4];
    {
        const float* vb0 = vpool + ((size_t)pb0 * BSZ * NHEAD + h) * DHEAD + c;
        const float* vb1 = vpool + ((size_t)pb1 * BSZ * NHEAD + h) * DHEAD + c;
#pragma unroll
        for (int j = 0; j < 4; ++j) {
            const float* r0 = vb0 + (size_t)(4 * quad + j) * (NHEAD * DHEAD);
            const float* r1 = vb1 + (size_t)(4 * quad + j) * (NHEAD * DHEAD);
#pragma unroll
            for (int ndv = 0; ndv < 4; ++ndv) {
                v0[j][ndv] = r0[16 * ndv];
                v1[j][ndv] = r1[16 * ndv];
            }
        }
    }
    // Fence: nothing below may be hoisted above / no load may sink below.
    __builtin_amdgcn_sched_barrier(0);

    // ---- Q B-frags ----
    H8 qb0, qb1;
    qb0.h[0]=(_Float16)q0.x; qb0.h[1]=(_Float16)q0.y; qb0.h[2]=(_Float16)q0.z; qb0.h[3]=(_Float16)q0.w;
    qb0.h[4]=(_Float16)q1.x; qb0.h[5]=(_Float16)q1.y; qb0.h[6]=(_Float16)q1.z; qb0.h[7]=(_Float16)q1.w;
    qb1.h[0]=(_Float16)q2.x; qb1.h[1]=(_Float16)q2.y; qb1.h[2]=(_Float16)q2.z; qb1.h[3]=(_Float16)q2.w;
    qb1.h[4]=(_Float16)q3.x; qb1.h[5]=(_Float16)q3.y; qb1.h[6]=(_Float16)q3.z; qb1.h[7]=(_Float16)q3.w;

    // ---- QK MFMAs: S^T[token][query] per tile ----
    const float4v z4 = {0.f, 0.f, 0.f, 0.f};
    H8 ka, kb;
    ka.h[0]=(_Float16)k0a.x; ka.h[1]=(_Float16)k0a.y; ka.h[2]=(_Float16)k0a.z; ka.h[3]=(_Float16)k0a.w;
    ka.h[4]=(_Float16)k0b.x; ka.h[5]=(_Float16)k0b.y; ka.h[6]=(_Float16)k0b.z; ka.h[7]=(_Float16)k0b.w;
    kb.h[0]=(_Float16)k0c.x; kb.h[1]=(_Float16)k0c.y; kb.h[2]=(_Float16)k0c.z; kb.h[3]=(_Float16)k0c.w;
    kb.h[4]=(_Float16)k0d.x; kb.h[5]=(_Float16)k0d.y; kb.h[6]=(_Float16)k0d.z; kb.h[7]=(_Float16)k0d.w;
    float4v st0 = __builtin_amdgcn_mfma_f32_16x16x32_f16(ka.v, qb0.v, z4, 0, 0, 0);
    st0 = __builtin_amdgcn_mfma_f32_16x16x32_f16(kb.v, qb1.v, st0, 0, 0, 0);
    ka.h[0]=(_Float16)k1a.x; ka.h[1]=(_Float16)k1a.y; ka.h[2]=(_Float16)k1a.z; ka.h[3]=(_Float16)k1a.w;
    ka.h[4]=(_Float16)k1b.x; ka.h[5]=(_Float16)k1b.y; ka.h[6]=(_Float16)k1b.z; ka.h[7]=(_Float16)k1b.w;
    kb.h[0]=(_Float16)k1c.x; kb.h[1]=(_Float16)k1c.y; kb.h[2]=(_Float16)k1c.z; kb.h[3]=(_Float16)k1c.w;
    kb.h[4]=(_Float16)k1d.x; kb.h[5]=(_Float16)k1d.y; kb.h[6]=(_Float16)k1d.z; kb.h[7]=(_Float16)k1d.w;
    float4v st1 = __builtin_amdgcn_mfma_f32_16x16x32_f16(ka.v, qb0.v, z4, 0, 0, 0);
    st1 = __builtin_amdgcn_mfma_f32_16x16x32_f16(kb.v, qb1.v, st1, 0, 0, 0);

    // ---- causal mask (per tile; only the last block's wave 3 is affected) ----
    if (tb0 + 15 > START_POS_C) {
#pragma unroll
        for (int r = 0; r < 4; ++r)
            if (tb0 + 4 * quad + r > START_POS_C + c) st0[r] = -INFINITY;
    }
    if (tb1 + 15 > START_POS_C) {
#pragma unroll
        for (int r = 0; r < 4; ++r)
            if (tb1 + 4 * quad + r > START_POS_C + c) st1[r] = -INFINITY;
    }

    // ---- single-shot softmax over this wave's 32 tokens (per query c) ----
    float tm = fmaxf(fmaxf(fmaxf(st0[0], st0[1]), fmaxf(st0[2], st0[3])),
                     fmaxf(fmaxf(st1[0], st1[1]), fmaxf(st1[2], st1[3])));
    tm = fmaxf(tm, __shfl_xor(tm, 16, 64));
    tm = fmaxf(tm, __shfl_xor(tm, 32, 64));
    H4 pa0, pa1;
    pa0.h[0]=(_Float16)exp2f(st0[0]-tm); pa0.h[1]=(_Float16)exp2f(st0[1]-tm);
    pa0.h[2]=(_Float16)exp2f(st0[2]-tm); pa0.h[3]=(_Float16)exp2f(st0[3]-tm);
    pa1.h[0]=(_Float16)exp2f(st1[0]-tm); pa1.h[1]=(_Float16)exp2f(st1[1]-tm);
    pa1.h[2]=(_Float16)exp2f(st1[2]-tm); pa1.h[3]=(_Float16)exp2f(st1[3]-tm);
    float ts = ((float)pa0.h[0] + (float)pa0.h[1]) + ((float)pa0.h[2] + (float)pa0.h[3])
             + ((float)pa1.h[0] + (float)pa1.h[1]) + ((float)pa1.h[2] + (float)pa1.h[3]);
    ts += __shfl_xor(ts, 16, 64);
    ts += __shfl_xor(ts, 32, 64);

    // ---- PV MFMAs (no rescale — single shot) ----
    float4v acc[4];
#pragma unroll
    for (int i = 0; i < 4; ++i) acc[i] = z4;
#pragma unroll
    for (int ndv = 0; ndv < 4; ++ndv) {
        H4 bf;
        bf.h[0]=(_Float16)v0[0][ndv]; bf.h[1]=(_Float16)v0[1][ndv];
        bf.h[2]=(_Float16)v0[2][ndv]; bf.h[3]=(_Float16)v0[3][ndv];
        acc[ndv] = __builtin_amdgcn_mfma_f32_16x16x16f16(pa0.v, bf.v, acc[ndv], 0, 0, 0);
        bf.h[0]=(_Float16)v1[0][ndv]; bf.h[1]=(_Float16)v1[1][ndv];
        bf.h[2]=(_Float16)v1[2][ndv]; bf.h[3]=(_Float16)v1[3][ndv];
        acc[ndv] = __builtin_amdgcn_mfma_f32_16x16x16f16(pa1.v, bf.v, acc[ndv], 0, 0, 0);
    }

    // ---- in-block merge of 4 wave-partials ----
#pragma unroll
    for (int ndv = 0; ndv < 4; ++ndv)
#pragma unroll
        for (int r = 0; r < 4; ++r)
            sacc[w][4 * quad + r][16 * ndv + c] = acc[ndv][r];
    if (quad == 0) { sm[w][c] = tm; sse[w][c] = ts; }
    __syncthreads();

    const int q = tid >> 4;
    const int dseg = tid & 15;
    float m0 = sm[0][q], m1 = sm[1][q], m2 = sm[2][q], m3 = sm[3][q];
    float M = fmaxf(fmaxf(m0, m1), fmaxf(m2, m3));
    float u0 = exp2f(m0 - M), u1 = exp2f(m1 - M), u2 = exp2f(m2 - M), u3 = exp2f(m3 - M);
    float den = u0 * sse[0][q] + u1 * sse[1][q] + u2 * sse[2][q] + u3 * sse[3][q];
    float4v num = u0 * (*(const float4v*)&sacc[0][q][4 * dseg])
                + u1 * (*(const float4v*)&sacc[1][q][4 * dseg])
                + u2 * (*(const float4v*)&sacc[2][q][4 * dseg])
                + u3 * (*(const float4v*)&sacc[3][q][4 * dseg]);
    const size_t ob = ((size_t)(h * SPLITS + s) * L_TOK + q) * DHEAD + 4 * dseg;
    *(float4v*)&accws[ob] = num;
    if (dseg == 0) {
        const size_t mb = (size_t)(h * SPLITS + s) * L_TOK + q;
        m_arr[mb] = M;
        se_arr[mb] = den;
    }
}

// ---------------------------------------------------------------------------
// Combine split partials v2: two-pass (max first, then weighted sum) so the
// 64 loads + 32 exp2 per thread are independent instead of a serial
// online-merge chain.
// ---------------------------------------------------------------------------
__global__ __launch_bounds__(256) void combine(const float* __restrict__ accws,
                                               const float* __restrict__ m_arr,
                                               const float* __restrict__ se_arr,
                                               float* __restrict__ attnws) {
    const int h = blockIdx.x >> 4;
    const int l = blockIdx.x & 15;
    const int w = threadIdx.x >> 6;
    const int lane = threadIdx.x & 63;
    __shared__ float sm[4], sse[4], sacc[4][64];

    const size_t base = (size_t)h * SPLITS * L_TOK + l;   // + s*L_TOK for split s

    float mreg[SPLITS / 4];
#pragma unroll
    for (int i = 0; i < SPLITS / 4; ++i)
        mreg[i] = m_arr[base + (size_t)(w + 4 * i) * L_TOK];
    float M = -INFINITY;
#pragma unroll
    for (int i = 0; i < SPLITS / 4; ++i) M = fmaxf(M, mreg[i]);

    float num = 0.f, den = 0.f;
#pragma unroll
    for (int i = 0; i < SPLITS / 4; ++i) {
        const size_t idx = base + (size_t)(w + 4 * i) * L_TOK;
        const float wgt = exp2f(mreg[i] - M);
        num = fmaf(wgt, accws[idx * DHEAD + lane], num);
        den = fmaf(wgt, se_arr[idx], den);
    }

    if (lane == 0) { sm[w] = M; sse[w] = den; }
    sacc[w][lane] = num;
    __syncthreads();
    if (w == 0) {
        const float M0 = fmaxf(fmaxf(sm[0], sm[1]), fmaxf(sm[2], sm[3]));
        float nn = 0.f, dd = 0.f;
#pragma unroll
        for (int i = 0; i < 4; ++i) {
            const float wgt = exp2f(sm[i] - M0);
            nn = fmaf(wgt, sacc[i][lane], nn);
            dd = fmaf(wgt, sse[i], dd);
        }
        attnws[(size_t)l * DMODEL + h * DHEAD + lane] = nn / dd;
    }
}

// ---------------------------------------------------------------------------
// Reduce split-K partials of final projection + bias -> d_out (unchanged).
// ---------------------------------------------------------------------------
__global__ __launch_bounds__(256) void proj_reduce(const float* __restrict__ part,
                                                   const float* __restrict__ bias,
                                                   float* __restrict__ out) {
    int tid = blockIdx.x * 256 + threadIdx.x;   // < 16384
    int n = tid & (DMODEL - 1);
    int l = tid >> 10;
    float s = bias[n];
#pragma unroll
    for (int kb = 0; kb < KSPLIT; ++kb)
        s += part[((size_t)kb * L_TOK + l) * DMODEL + n];
    out[tid] = s;
}

extern "C" void kernel_launch(void* const* d_in, const int* in_sizes, int n_in,
                              void* d_out, int out_size, void* d_ws, size_t ws_size,
                              hipStream_t stream) {
    const float* x       = (const float*)d_in[0];
    float* kpool         = (float*)d_in[1];
    float* vpool         = (float*)d_in[2];
    const float* W_attn  = (const float*)d_in[3];
    const float* b_attn  = (const float*)d_in[4];
    const float* W_proj  = (const float*)d_in[5];
    const float* b_proj  = (const float*)d_in[6];
    const int* block_ids = (const int*)d_in[7];
    float* ws  = (float*)d_ws;
    float* out = (float*)d_out;

    // 1) QKV projection (split-K partials; W read once, 16 rows/thread)
    gemm16<<<dim3(6, KSPLIT), 256, 0, stream>>>(x, W_attn, ws + OFF_QKVP, 3 * DMODEL);
    // 2) reduce + bias; q -> ws (scaled), new k/v -> pools (paged write)
    qkv_reduce_scatter<<<192, 256, 0, stream>>>(ws + OFF_QKVP, b_attn, block_ids,
                                                ws + OFF_QW, kpool, vpool);
    // 3) flash-decode attention over the full prefix (f16 MFMA, 4-wave blocks)
    paged_attn<<<dim3(NHEAD, SPLITS), 256, 0, stream>>>(kpool, vpool, block_ids,
                                                        ws + OFF_QW, ws + OFF_ACC,
                                                        ws + OFF_M, ws + OFF_SE);
    // 4) combine splits
    combine<<<NHEAD * L_TOK, 256, 0, stream>>>(ws + OFF_ACC, ws + OFF_M, ws + OFF_SE,
                                               ws + OFF_ATTN);
    // 5) output projection (split-K partials)
    gemm16<<<dim3(2, KSPLIT), 256, 0, stream>>>(ws + OFF_ATTN, W_proj, ws + OFF_PROJP, DMODEL);
    // 6) reduce + bias -> d_out
    proj_reduce<<<64, 256, 0, stream>>>(ws + OFF_PROJP, b_proj, out);
}

// Round 2
// 195.689 us; speedup vs baseline: 1.2646x; 1.2646x over previous
//
#include <hip/hip_runtime.h>
#include <math.h>

#define L_TOK 16
#define DMODEL 1024
#define NHEAD 16
#define DHEAD 64
#define NBLK 1024
#define BSZ 16
#define START_POS_C 16368
#define TTOT 16384
#define SPLITS 128
#define CHUNK 128          // tokens per block (4 waves x 32 tokens)
#define KSPLIT 16
#define QSCALE (0.125f * 1.4426950408889634f)   // 1/sqrt(64) * log2(e)

// workspace offsets, in floats (layout unchanged — 12.4 MB proven scale)
#define OFF_QKVP 0                                          // 16*16*3072 = 786432
#define OFF_QW   (OFF_QKVP + KSPLIT * L_TOK * 3 * DMODEL)   // 786432
#define OFF_ACC  (OFF_QW + NHEAD * L_TOK * DHEAD)           // 802816
#define OFF_M    (OFF_ACC + NHEAD * SPLITS * L_TOK * DHEAD) // 2899968
#define OFF_SE   (OFF_M + NHEAD * SPLITS * L_TOK)           // 2932736
#define OFF_ATTN (OFF_SE + NHEAD * SPLITS * L_TOK)          // 2965504
#define OFF_PROJP (OFF_ATTN + L_TOK * DMODEL)               // 2981888

typedef _Float16 half4_t __attribute__((ext_vector_type(4)));
typedef _Float16 half8_t __attribute__((ext_vector_type(8)));
typedef float float4v __attribute__((ext_vector_type(4)));

union H8 { _Float16 h[8]; half8_t v; };
union H4 { _Float16 h[4]; half4_t v; };

// Forced-order global loads: asm volatile keeps issue order and live dests,
// so all loads of a burst are in flight before the hand-placed s_waitcnt.
#define GL4(dst, p, o) asm volatile("global_load_dwordx4 %0, %1, off offset:" #o : "=v"(dst) : "v"(p))
#define GL1(dst, p, o) asm volatile("global_load_dword %0, %1, off offset:" #o : "=v"(dst) : "v"(p))

// ---------------------------------------------------------------------------
// Split-K partial GEMM v3. Block = 256 cols x 64 ks; thread owns 1 col, all
// 16 rows. W loads in explicit 16-deep double-buffered batches (pinned with
// sched_barrier so they cannot sink into the FMA chains — round-1 lesson).
// x staged transposed in LDS, rows 20 floats (16B-aligned, broadcast b128).
// grid = (ncols/256, KSPLIT).
// ---------------------------------------------------------------------------
__device__ __forceinline__ void load_batch(float* buf, const float* Wp, int bk, int ncols) {
#pragma unroll
    for (int i = 0; i < 16; ++i) buf[i] = Wp[(size_t)(bk + i) * ncols];
}

__device__ __forceinline__ void fma_batch(float4v* acc_, const float* buf,
                                          const float* sxT, int bk) {
#pragma unroll
    for (int i = 0; i < 16; ++i) {
        const float wv_ = buf[i];
        const float4v* xp = (const float4v*)&sxT[(bk + i) * 20];
        float4v xa = xp[0], xb = xp[1], xc = xp[2], xd = xp[3];
        acc_[0] += xa * wv_;
        acc_[1] += xb * wv_;
        acc_[2] += xc * wv_;
        acc_[3] += xd * wv_;
    }
}

__global__ __launch_bounds__(256) void gemm_part(const float* __restrict__ x,
                                                 const float* __restrict__ W,
                                                 float* __restrict__ part,
                                                 int ncols) {
    const int col = blockIdx.x * 256 + threadIdx.x;
    const int k0 = blockIdx.y * (DMODEL / KSPLIT);   // 64 ks per block

    __shared__ __align__(16) float sxT[64 * 20];     // [k][l], padded row = 80B
#pragma unroll
    for (int i = threadIdx.x; i < 64 * 16; i += 256) {
        int k = i & 63, l = i >> 6;                  // consecutive tid -> consecutive k
        sxT[k * 20 + l] = x[(size_t)l * DMODEL + k0 + k];
    }

    const float* Wp = W + (size_t)k0 * ncols + col;
    float wa[16], wb[16];
    load_batch(wa, Wp, 0, ncols);
    load_batch(wb, Wp, 16, ncols);
    __builtin_amdgcn_sched_barrier(0);
    __syncthreads();

    float4v acc_[4];
#pragma unroll
    for (int g = 0; g < 4; ++g) acc_[g] = (float4v){0.f, 0.f, 0.f, 0.f};

    fma_batch(acc_, wa, sxT, 0);
    load_batch(wa, Wp, 32, ncols);
    __builtin_amdgcn_sched_barrier(0);
    fma_batch(acc_, wb, sxT, 16);
    load_batch(wb, Wp, 48, ncols);
    __builtin_amdgcn_sched_barrier(0);
    fma_batch(acc_, wa, sxT, 32);
    fma_batch(acc_, wb, sxT, 48);

    const size_t base = ((size_t)blockIdx.y * L_TOK) * ncols + col;
#pragma unroll
    for (int g = 0; g < 4; ++g)
#pragma unroll
        for (int j = 0; j < 4; ++j)
            part[base + (size_t)(4 * g + j) * ncols] = acc_[g][j];
}

// ---------------------------------------------------------------------------
// Reduce split-K partials of QKV, add bias, scatter (unchanged).
// ---------------------------------------------------------------------------
__global__ __launch_bounds__(256) void qkv_reduce_scatter(const float* __restrict__ part,
                                                          const float* __restrict__ b_attn,
                                                          const int* __restrict__ block_ids,
                                                          float* __restrict__ qws,
                                                          float* __restrict__ kpool,
                                                          float* __restrict__ vpool) {
    int tid = blockIdx.x * 256 + threadIdx.x;
    int n = tid % (3 * DMODEL);
    int l = tid / (3 * DMODEL);
    float s = b_attn[n];
#pragma unroll
    for (int kb = 0; kb < KSPLIT; ++kb)
        s += part[((size_t)kb * L_TOK + l) * (3 * DMODEL) + n];
    int sec = n >> 10;
    int m = n & (DMODEL - 1);
    int h = m >> 6;
    int dd = m & 63;
    if (sec == 0) {
        qws[(h * L_TOK + l) * DHEAD + dd] = s * QSCALE;
    } else {
        int pos = START_POS_C + l;
        int blk = block_ids[pos >> 4];
        int off = pos & 15;
        size_t idx = (((size_t)blk * BSZ + off) * NHEAD + h) * DHEAD + dd;
        if (sec == 1) kpool[idx] = s;
        else          vpool[idx] = s;
    }
}

// ---------------------------------------------------------------------------
// Flash-decode paged attention v7. Loads via inline-asm global_load with
// hand-counted waits: issue Q(4) K(8) V(32) dwordx4/dword in forced order,
// s_waitcnt vmcnt(32) -> Q+K ready (V still in flight under QK+softmax),
// s_waitcnt vmcnt(0) -> V ready for PV. Counted waits are safe vs extra
// compiler loads because vmcnt retires in order. launch_bounds (256,3)
// gives the allocator headroom (~170) so the 80 live load dests don't spill.
// ---------------------------------------------------------------------------
__global__ __launch_bounds__(256, 3) void paged_attn(const float* __restrict__ kpool,
                                                     const float* __restrict__ vpool,
                                                     const int* __restrict__ block_ids,
                                                     const float* __restrict__ qws,
                                                     float* __restrict__ accws,
                                                     float* __restrict__ m_arr,
                                                     float* __restrict__ se_arr) {
    const int h = blockIdx.x;
    const int s = blockIdx.y;
    const int tid = threadIdx.x;
    const int w = tid >> 6;
    const int lane = tid & 63;
    const int c = lane & 15;
    const int quad = lane >> 4;

    __shared__ __align__(16) float sacc[4][16][68];   // stride 68: 2-way banks, 16B rows
    __shared__ float sm[4][16], sse[4][16];

    const int pb0 = block_ids[s * 8 + 2 * w];
    const int pb1 = block_ids[s * 8 + 2 * w + 1];
    const int tb0 = s * CHUNK + w * 32;
    const int tb1 = tb0 + 16;

    // ---- base addresses ----
    const float* qr  = qws + ((size_t)(h * L_TOK + c)) * DHEAD + quad * 8;
    const float* kr0 = kpool + (((size_t)pb0 * BSZ + c) * NHEAD + h) * DHEAD + quad * 8;
    const float* kr1 = kpool + (((size_t)pb1 * BSZ + c) * NHEAD + h) * DHEAD + quad * 8;
    const float* vb0 = vpool + ((size_t)pb0 * BSZ * NHEAD + h) * DHEAD + c;
    const float* vb1 = vpool + ((size_t)pb1 * BSZ * NHEAD + h) * DHEAD + c;

    // ---- forced burst: 44 loads issued before any wait ----
    float4v q0, q1, q2, q3, k0a, k0b, k0c, k0d, k1a, k1b, k1c, k1d;
    GL4(q0, qr, 0); GL4(q1, qr, 16); GL4(q2, qr, 128); GL4(q3, qr, 144);
    GL4(k0a, kr0, 0); GL4(k0b, kr0, 16); GL4(k0c, kr0, 128); GL4(k0d, kr0, 144);
    GL4(k1a, kr1, 0); GL4(k1b, kr1, 16); GL4(k1c, kr1, 128); GL4(k1d, kr1, 144);
    float v0_[4][4], v1_[4][4];
#pragma unroll
    for (int j = 0; j < 4; ++j) {
        const float* r0 = vb0 + (size_t)(4 * quad + j) * (NHEAD * DHEAD);
        GL1(v0_[j][0], r0, 0); GL1(v0_[j][1], r0, 64);
        GL1(v0_[j][2], r0, 128); GL1(v0_[j][3], r0, 192);
    }
#pragma unroll
    for (int j = 0; j < 4; ++j) {
        const float* r1 = vb1 + (size_t)(4 * quad + j) * (NHEAD * DHEAD);
        GL1(v1_[j][0], r1, 0); GL1(v1_[j][1], r1, 64);
        GL1(v1_[j][2], r1, 128); GL1(v1_[j][3], r1, 192);
    }
    // Q + K retired (12 oldest of 44); V's 32 still outstanding.
    asm volatile("s_waitcnt vmcnt(32)" ::: "memory");
    __builtin_amdgcn_sched_barrier(0);

    // ---- Q B-frags ----
    H8 qb0, qb1;
    qb0.h[0]=(_Float16)q0[0]; qb0.h[1]=(_Float16)q0[1]; qb0.h[2]=(_Float16)q0[2]; qb0.h[3]=(_Float16)q0[3];
    qb0.h[4]=(_Float16)q1[0]; qb0.h[5]=(_Float16)q1[1]; qb0.h[6]=(_Float16)q1[2]; qb0.h[7]=(_Float16)q1[3];
    qb1.h[0]=(_Float16)q2[0]; qb1.h[1]=(_Float16)q2[1]; qb1.h[2]=(_Float16)q2[2]; qb1.h[3]=(_Float16)q2[3];
    qb1.h[4]=(_Float16)q3[0]; qb1.h[5]=(_Float16)q3[1]; qb1.h[6]=(_Float16)q3[2]; qb1.h[7]=(_Float16)q3[3];

    // ---- QK MFMAs: S^T[token][query] per tile ----
    const float4v z4 = {0.f, 0.f, 0.f, 0.f};
    H8 ka, kb;
    ka.h[0]=(_Float16)k0a[0]; ka.h[1]=(_Float16)k0a[1]; ka.h[2]=(_Float16)k0a[2]; ka.h[3]=(_Float16)k0a[3];
    ka.h[4]=(_Float16)k0b[0]; ka.h[5]=(_Float16)k0b[1]; ka.h[6]=(_Float16)k0b[2]; ka.h[7]=(_Float16)k0b[3];
    kb.h[0]=(_Float16)k0c[0]; kb.h[1]=(_Float16)k0c[1]; kb.h[2]=(_Float16)k0c[2]; kb.h[3]=(_Float16)k0c[3];
    kb.h[4]=(_Float16)k0d[0]; kb.h[5]=(_Float16)k0d[1]; kb.h[6]=(_Float16)k0d[2]; kb.h[7]=(_Float16)k0d[3];
    float4v st0 = __builtin_amdgcn_mfma_f32_16x16x32_f16(ka.v, qb0.v, z4, 0, 0, 0);
    st0 = __builtin_amdgcn_mfma_f32_16x16x32_f16(kb.v, qb1.v, st0, 0, 0, 0);
    ka.h[0]=(_Float16)k1a[0]; ka.h[1]=(_Float16)k1a[1]; ka.h[2]=(_Float16)k1a[2]; ka.h[3]=(_Float16)k1a[3];
    ka.h[4]=(_Float16)k1b[0]; ka.h[5]=(_Float16)k1b[1]; ka.h[6]=(_Float16)k1b[2]; ka.h[7]=(_Float16)k1b[3];
    kb.h[0]=(_Float16)k1c[0]; kb.h[1]=(_Float16)k1c[1]; kb.h[2]=(_Float16)k1c[2]; kb.h[3]=(_Float16)k1c[3];
    kb.h[4]=(_Float16)k1d[0]; kb.h[5]=(_Float16)k1d[1]; kb.h[6]=(_Float16)k1d[2]; kb.h[7]=(_Float16)k1d[3];
    float4v st1 = __builtin_amdgcn_mfma_f32_16x16x32_f16(ka.v, qb0.v, z4, 0, 0, 0);
    st1 = __builtin_amdgcn_mfma_f32_16x16x32_f16(kb.v, qb1.v, st1, 0, 0, 0);

    // ---- causal mask (per tile; only the last block's wave 3 is affected) ----
    if (tb0 + 15 > START_POS_C) {
#pragma unroll
        for (int r = 0; r < 4; ++r)
            if (tb0 + 4 * quad + r > START_POS_C + c) st0[r] = -INFINITY;
    }
    if (tb1 + 15 > START_POS_C) {
#pragma unroll
        for (int r = 0; r < 4; ++r)
            if (tb1 + 4 * quad + r > START_POS_C + c) st1[r] = -INFINITY;
    }

    // ---- single-shot softmax over this wave's 32 tokens (per query c) ----
    float tm = fmaxf(fmaxf(fmaxf(st0[0], st0[1]), fmaxf(st0[2], st0[3])),
                     fmaxf(fmaxf(st1[0], st1[1]), fmaxf(st1[2], st1[3])));
    tm = fmaxf(tm, __shfl_xor(tm, 16, 64));
    tm = fmaxf(tm, __shfl_xor(tm, 32, 64));
    H4 pa0, pa1;
    pa0.h[0]=(_Float16)exp2f(st0[0]-tm); pa0.h[1]=(_Float16)exp2f(st0[1]-tm);
    pa0.h[2]=(_Float16)exp2f(st0[2]-tm); pa0.h[3]=(_Float16)exp2f(st0[3]-tm);
    pa1.h[0]=(_Float16)exp2f(st1[0]-tm); pa1.h[1]=(_Float16)exp2f(st1[1]-tm);
    pa1.h[2]=(_Float16)exp2f(st1[2]-tm); pa1.h[3]=(_Float16)exp2f(st1[3]-tm);
    float ts = ((float)pa0.h[0] + (float)pa0.h[1]) + ((float)pa0.h[2] + (float)pa0.h[3])
             + ((float)pa1.h[0] + (float)pa1.h[1]) + ((float)pa1.h[2] + (float)pa1.h[3]);
    ts += __shfl_xor(ts, 16, 64);
    ts += __shfl_xor(ts, 32, 64);

    // ---- V ready now ----
    asm volatile("s_waitcnt vmcnt(0)" ::: "memory");
    __builtin_amdgcn_sched_barrier(0);

    // ---- PV MFMAs (no rescale — single shot) ----
    float4v acc[4];
#pragma unroll
    for (int i = 0; i < 4; ++i) acc[i] = z4;
#pragma unroll
    for (int ndv = 0; ndv < 4; ++ndv) {
        H4 bf;
        bf.h[0]=(_Float16)v0_[0][ndv]; bf.h[1]=(_Float16)v0_[1][ndv];
        bf.h[2]=(_Float16)v0_[2][ndv]; bf.h[3]=(_Float16)v0_[3][ndv];
        acc[ndv] = __builtin_amdgcn_mfma_f32_16x16x16f16(pa0.v, bf.v, acc[ndv], 0, 0, 0);
        bf.h[0]=(_Float16)v1_[0][ndv]; bf.h[1]=(_Float16)v1_[1][ndv];
        bf.h[2]=(_Float16)v1_[2][ndv]; bf.h[3]=(_Float16)v1_[3][ndv];
        acc[ndv] = __builtin_amdgcn_mfma_f32_16x16x16f16(pa1.v, bf.v, acc[ndv], 0, 0, 0);
    }

    // ---- in-block merge of 4 wave-partials ----
#pragma unroll
    for (int ndv = 0; ndv < 4; ++ndv)
#pragma unroll
        for (int r = 0; r < 4; ++r)
            sacc[w][4 * quad + r][16 * ndv + c] = acc[ndv][r];
    if (quad == 0) { sm[w][c] = tm; sse[w][c] = ts; }
    __syncthreads();

    const int q = tid >> 4;
    const int dseg = tid & 15;
    float m0 = sm[0][q], m1 = sm[1][q], m2 = sm[2][q], m3 = sm[3][q];
    float M = fmaxf(fmaxf(m0, m1), fmaxf(m2, m3));
    float u0 = exp2f(m0 - M), u1 = exp2f(m1 - M), u2 = exp2f(m2 - M), u3 = exp2f(m3 - M);
    float den = u0 * sse[0][q] + u1 * sse[1][q] + u2 * sse[2][q] + u3 * sse[3][q];
    float4v num = u0 * (*(const float4v*)&sacc[0][q][4 * dseg])
                + u1 * (*(const float4v*)&sacc[1][q][4 * dseg])
                + u2 * (*(const float4v*)&sacc[2][q][4 * dseg])
                + u3 * (*(const float4v*)&sacc[3][q][4 * dseg]);
    const size_t ob = ((size_t)(h * SPLITS + s) * L_TOK + q) * DHEAD + 4 * dseg;
    *(float4v*)&accws[ob] = num;
    if (dseg == 0) {
        const size_t mb = (size_t)(h * SPLITS + s) * L_TOK + q;
        m_arr[mb] = M;
        se_arr[mb] = den;
    }
}

// ---------------------------------------------------------------------------
// Combine split partials (two-pass, independent loads — unchanged from r1).
// ---------------------------------------------------------------------------
__global__ __launch_bounds__(256) void combine(const float* __restrict__ accws,
                                               const float* __restrict__ m_arr,
                                               const float* __restrict__ se_arr,
                                               float* __restrict__ attnws) {
    const int h = blockIdx.x >> 4;
    const int l = blockIdx.x & 15;
    const int w = threadIdx.x >> 6;
    const int lane = threadIdx.x & 63;
    __shared__ float sm[4], sse[4], sacc[4][64];

    const size_t base = (size_t)h * SPLITS * L_TOK + l;

    float mreg[SPLITS / 4];
#pragma unroll
    for (int i = 0; i < SPLITS / 4; ++i)
        mreg[i] = m_arr[base + (size_t)(w + 4 * i) * L_TOK];
    float M = -INFINITY;
#pragma unroll
    for (int i = 0; i < SPLITS / 4; ++i) M = fmaxf(M, mreg[i]);

    float num = 0.f, den = 0.f;
#pragma unroll
    for (int i = 0; i < SPLITS / 4; ++i) {
        const size_t idx = base + (size_t)(w + 4 * i) * L_TOK;
        const float wgt = exp2f(mreg[i] - M);
        num = fmaf(wgt, accws[idx * DHEAD + lane], num);
        den = fmaf(wgt, se_arr[idx], den);
    }

    if (lane == 0) { sm[w] = M; sse[w] = den; }
    sacc[w][lane] = num;
    __syncthreads();
    if (w == 0) {
        const float M0 = fmaxf(fmaxf(sm[0], sm[1]), fmaxf(sm[2], sm[3]));
        float nn = 0.f, dd = 0.f;
#pragma unroll
        for (int i = 0; i < 4; ++i) {
            const float wgt = exp2f(sm[i] - M0);
            nn = fmaf(wgt, sacc[i][lane], nn);
            dd = fmaf(wgt, sse[i], dd);
        }
        attnws[(size_t)l * DMODEL + h * DHEAD + lane] = nn / dd;
    }
}

// ---------------------------------------------------------------------------
// Reduce split-K partials of final projection + bias -> d_out (unchanged).
// ---------------------------------------------------------------------------
__global__ __launch_bounds__(256) void proj_reduce(const float* __restrict__ part,
                                                   const float* __restrict__ bias,
                                                   float* __restrict__ out) {
    int tid = blockIdx.x * 256 + threadIdx.x;   // < 16384
    int n = tid & (DMODEL - 1);
    int l = tid >> 10;
    float s = bias[n];
#pragma unroll
    for (int kb = 0; kb < KSPLIT; ++kb)
        s += part[((size_t)kb * L_TOK + l) * DMODEL + n];
    out[tid] = s;
}

extern "C" void kernel_launch(void* const* d_in, const int* in_sizes, int n_in,
                              void* d_out, int out_size, void* d_ws, size_t ws_size,
                              hipStream_t stream) {
    const float* x       = (const float*)d_in[0];
    float* kpool         = (float*)d_in[1];
    float* vpool         = (float*)d_in[2];
    const float* W_attn  = (const float*)d_in[3];
    const float* b_attn  = (const float*)d_in[4];
    const float* W_proj  = (const float*)d_in[5];
    const float* b_proj  = (const float*)d_in[6];
    const int* block_ids = (const int*)d_in[7];
    float* ws  = (float*)d_ws;
    float* out = (float*)d_out;

    // 1) QKV projection (split-K partials; batched W loads, 16 rows/thread)
    gemm_part<<<dim3(12, KSPLIT), 256, 0, stream>>>(x, W_attn, ws + OFF_QKVP, 3 * DMODEL);
    // 2) reduce + bias; q -> ws (scaled), new k/v -> pools (paged write)
    qkv_reduce_scatter<<<192, 256, 0, stream>>>(ws + OFF_QKVP, b_attn, block_ids,
                                                ws + OFF_QW, kpool, vpool);
    // 3) flash-decode attention (asm load burst + counted waits)
    paged_attn<<<dim3(NHEAD, SPLITS), 256, 0, stream>>>(kpool, vpool, block_ids,
                                                        ws + OFF_QW, ws + OFF_ACC,
                                                        ws + OFF_M, ws + OFF_SE);
    // 4) combine splits
    combine<<<NHEAD * L_TOK, 256, 0, stream>>>(ws + OFF_ACC, ws + OFF_M, ws + OFF_SE,
                                               ws + OFF_ATTN);
    // 5) output projection (split-K partials)
    gemm_part<<<dim3(4, KSPLIT), 256, 0, stream>>>(ws + OFF_ATTN, W_proj, ws + OFF_PROJP, DMODEL);
    // 6) reduce + bias -> d_out
    proj_reduce<<<64, 256, 0, stream>>>(ws + OFF_PROJP, b_proj, out);
}

// Round 3
// 194.031 us; speedup vs baseline: 1.2754x; 1.0085x over previous
//
#include <hip/hip_runtime.h>
#include <math.h>

#define L_TOK 16
#define DMODEL 1024
#define NHEAD 16
#define DHEAD 64
#define NBLK 1024
#define BSZ 16
#define START_POS_C 16368
#define TTOT 16384
#define SPLITS 128
#define CHUNK 128          // tokens per block (4 waves x 32 tokens)
#define KSPLIT 16
#define QSCALE (0.125f * 1.4426950408889634f)   // 1/sqrt(64) * log2(e)

// workspace offsets, in floats (layout unchanged — 12.4 MB proven scale)
#define OFF_QKVP 0                                          // 16*16*3072 = 786432
#define OFF_QW   (OFF_QKVP + KSPLIT * L_TOK * 3 * DMODEL)   // 786432
#define OFF_ACC  (OFF_QW + NHEAD * L_TOK * DHEAD)           // 802816
#define OFF_M    (OFF_ACC + NHEAD * SPLITS * L_TOK * DHEAD) // 2899968
#define OFF_SE   (OFF_M + NHEAD * SPLITS * L_TOK)           // 2932736
#define OFF_ATTN (OFF_SE + NHEAD * SPLITS * L_TOK)          // 2965504
#define OFF_PROJP (OFF_ATTN + L_TOK * DMODEL)               // 2981888

typedef _Float16 half4_t __attribute__((ext_vector_type(4)));
typedef _Float16 half8_t __attribute__((ext_vector_type(8)));
typedef float float4v __attribute__((ext_vector_type(4)));

union H8 { _Float16 h[8]; half8_t v; };
union H4 { _Float16 h[4]; half4_t v; };

// LDS-DMA: 64 lanes x 16B -> lds_base + lane*16 (no VGPR dest, so the
// compiler cannot rematerialize/serialize the burst — rounds 0-2 lesson).
#define LDS_DMA16(gsrc, ldst)                                                        \
    __builtin_amdgcn_global_load_lds(                                                \
        (const __attribute__((address_space(1))) void*)(gsrc),                       \
        (__attribute__((address_space(3))) void*)(ldst), 16, 0, 0)

// ---------------------------------------------------------------------------
// Split-K partial GEMM (round-2 proven). Block = 256 cols x 64 ks; thread
// owns 1 col, all 16 rows. W loads in 16-deep double-buffered batches pinned
// with sched_barrier. x transposed in LDS (broadcast b128 reads).
// ---------------------------------------------------------------------------
__device__ __forceinline__ void load_batch(float* buf, const float* Wp, int bk, int ncols) {
#pragma unroll
    for (int i = 0; i < 16; ++i) buf[i] = Wp[(size_t)(bk + i) * ncols];
}

__device__ __forceinline__ void fma_batch(float4v* acc_, const float* buf,
                                          const float* sxT, int bk) {
#pragma unroll
    for (int i = 0; i < 16; ++i) {
        const float wv_ = buf[i];
        const float4v* xp = (const float4v*)&sxT[(bk + i) * 20];
        float4v xa = xp[0], xb = xp[1], xc = xp[2], xd = xp[3];
        acc_[0] += xa * wv_;
        acc_[1] += xb * wv_;
        acc_[2] += xc * wv_;
        acc_[3] += xd * wv_;
    }
}

__global__ __launch_bounds__(256) void gemm_part(const float* __restrict__ x,
                                                 const float* __restrict__ W,
                                                 float* __restrict__ part,
                                                 int ncols) {
    const int col = blockIdx.x * 256 + threadIdx.x;
    const int k0 = blockIdx.y * (DMODEL / KSPLIT);   // 64 ks per block

    __shared__ __align__(16) float sxT[64 * 20];     // [k][l], padded row = 80B
#pragma unroll
    for (int i = threadIdx.x; i < 64 * 16; i += 256) {
        int k = i & 63, l = i >> 6;                  // consecutive tid -> consecutive k
        sxT[k * 20 + l] = x[(size_t)l * DMODEL + k0 + k];
    }

    const float* Wp = W + (size_t)k0 * ncols + col;
    float wa[16], wb[16];
    load_batch(wa, Wp, 0, ncols);
    load_batch(wb, Wp, 16, ncols);
    __builtin_amdgcn_sched_barrier(0);
    __syncthreads();

    float4v acc_[4];
#pragma unroll
    for (int g = 0; g < 4; ++g) acc_[g] = (float4v){0.f, 0.f, 0.f, 0.f};

    fma_batch(acc_, wa, sxT, 0);
    load_batch(wa, Wp, 32, ncols);
    __builtin_amdgcn_sched_barrier(0);
    fma_batch(acc_, wb, sxT, 16);
    load_batch(wb, Wp, 48, ncols);
    __builtin_amdgcn_sched_barrier(0);
    fma_batch(acc_, wa, sxT, 32);
    fma_batch(acc_, wb, sxT, 48);

    const size_t base = ((size_t)blockIdx.y * L_TOK) * ncols + col;
#pragma unroll
    for (int g = 0; g < 4; ++g)
#pragma unroll
        for (int j = 0; j < 4; ++j)
            part[base + (size_t)(4 * g + j) * ncols] = acc_[g][j];
}

// ---------------------------------------------------------------------------
// Reduce split-K partials of QKV, add bias, scatter. v2: load all 16 partials
// into an array (independent loads), tree-sum — breaks the serial
// load->add->load chain that latency-serialized v1.
// ---------------------------------------------------------------------------
__global__ __launch_bounds__(256) void qkv_reduce_scatter(const float* __restrict__ part,
                                                          const float* __restrict__ b_attn,
                                                          const int* __restrict__ block_ids,
                                                          float* __restrict__ qws,
                                                          float* __restrict__ kpool,
                                                          float* __restrict__ vpool) {
    int tid = blockIdx.x * 256 + threadIdx.x;
    int n = tid % (3 * DMODEL);
    int l = tid / (3 * DMODEL);
    float p[KSPLIT];
#pragma unroll
    for (int kb = 0; kb < KSPLIT; ++kb)
        p[kb] = part[((size_t)kb * L_TOK + l) * (3 * DMODEL) + n];
    float s = b_attn[n];
#pragma unroll
    for (int st = 1; st < KSPLIT; st <<= 1)
#pragma unroll
        for (int i = 0; i < KSPLIT; i += 2 * st) p[i] += p[i + st];
    s += p[0];
    int sec = n >> 10;
    int m = n & (DMODEL - 1);
    int h = m >> 6;
    int dd = m & 63;
    if (sec == 0) {
        qws[(h * L_TOK + l) * DHEAD + dd] = s * QSCALE;
    } else {
        int pos = START_POS_C + l;
        int blk = block_ids[pos >> 4];
        int off = pos & 15;
        size_t idx = (((size_t)blk * BSZ + off) * NHEAD + h) * DHEAD + dd;
        if (sec == 1) kpool[idx] = s;
        else          vpool[idx] = s;
    }
}

// ---------------------------------------------------------------------------
// Flash-decode paged attention v8: K/V staged to LDS via global_load_lds
// (16B/lane DMA — no VGPR dest, burst cannot be serialized by regalloc).
// Global source is pre-swizzled (col ^ ((row&7)<<2), 4-float granularity);
// the same involution is applied on the LDS-read side, so K b128 frag reads
// spread over all 32 banks and V b32 gathers are 2-way (free).
// LDS: K[128][64] | V[128][64] = 64KB; sacc merge buffer ALIASES the K
// region (dead after QK; barrier-protected). 66KB -> 2 blocks/CU; in-flight
// 128KB/CU vs ~2KB before.
// ---------------------------------------------------------------------------
__global__ __launch_bounds__(256, 2) void paged_attn(const float* __restrict__ kpool,
                                                     const float* __restrict__ vpool,
                                                     const int* __restrict__ block_ids,
                                                     const float* __restrict__ qws,
                                                     float* __restrict__ accws,
                                                     float* __restrict__ m_arr,
                                                     float* __restrict__ se_arr) {
    const int h = blockIdx.x;
    const int s = blockIdx.y;
    const int tid = threadIdx.x;
    const int w = tid >> 6;
    const int lane = tid & 63;
    const int c = lane & 15;
    const int quad = lane >> 4;

    __shared__ __align__(16) float smem[16384];   // K: [0,8192)  V: [8192,16384) floats
    __shared__ float sm[4][16], sse[4][16];
    float* Klds = smem;
    float* Vlds = smem + 8192;
    float (*sacc)[16][68] = (float (*)[16][68])smem;   // alias of K region

    const int pb0 = block_ids[s * 8 + 2 * w];
    const int pb1 = block_ids[s * 8 + 2 * w + 1];
    const int tb0 = s * CHUNK + w * 32;
    const int tb1 = tb0 + 16;

    // ---- LDS-DMA issue: 16 x 1KB per wave (K: 8, V: 8) ----
    // per-lane source byte offset within a 4-row group; lane covers row
    // (base + quad), floats [(c*4)^swz .. +3], swz = ((row&7)<<2).
    const int off0 = quad * 4096 + (((c * 4) ^ (quad * 4)) * 4);        // rows r%8==0
    const int off4 = quad * 4096 + (((c * 4) ^ (quad * 4 + 16)) * 4);   // rows r%8==4
    const char* kg0 = (const char*)(kpool + ((size_t)pb0 * 256 + h) * 64);
    const char* kg1 = (const char*)(kpool + ((size_t)pb1 * 256 + h) * 64);
    const char* vg0 = (const char*)(vpool + ((size_t)pb0 * 256 + h) * 64);
    const char* vg1 = (const char*)(vpool + ((size_t)pb1 * 256 + h) * 64);
    float* kwb = Klds + (w * 32) * 64;
    float* vwb = Vlds + (w * 32) * 64;

    LDS_DMA16(kg0 + 0 * 4096 + off0, kwb + 0 * 64);
    LDS_DMA16(kg0 + 4 * 4096 + off4, kwb + 4 * 64);
    LDS_DMA16(kg0 + 8 * 4096 + off0, kwb + 8 * 64);
    LDS_DMA16(kg0 + 12 * 4096 + off4, kwb + 12 * 64);
    LDS_DMA16(kg1 + 0 * 4096 + off0, kwb + 16 * 64);
    LDS_DMA16(kg1 + 4 * 4096 + off4, kwb + 20 * 64);
    LDS_DMA16(kg1 + 8 * 4096 + off0, kwb + 24 * 64);
    LDS_DMA16(kg1 + 12 * 4096 + off4, kwb + 28 * 64);
    LDS_DMA16(vg0 + 0 * 4096 + off0, vwb + 0 * 64);
    LDS_DMA16(vg0 + 4 * 4096 + off4, vwb + 4 * 64);
    LDS_DMA16(vg0 + 8 * 4096 + off0, vwb + 8 * 64);
    LDS_DMA16(vg0 + 12 * 4096 + off4, vwb + 12 * 64);
    LDS_DMA16(vg1 + 0 * 4096 + off0, vwb + 16 * 64);
    LDS_DMA16(vg1 + 4 * 4096 + off4, vwb + 20 * 64);
    LDS_DMA16(vg1 + 8 * 4096 + off0, vwb + 24 * 64);
    LDS_DMA16(vg1 + 12 * 4096 + off4, vwb + 28 * 64);

    // ---- Q rows (plain loads; retire under the same wait) ----
    const float* qr = qws + ((size_t)(h * L_TOK + c)) * DHEAD + quad * 8;
    float4 q0 = *(const float4*)(qr);
    float4 q1 = *(const float4*)(qr + 4);
    float4 q2 = *(const float4*)(qr + 32);
    float4 q3 = *(const float4*)(qr + 36);

    // Each wave reads only its own LDS rows -> per-wave vmcnt wait, no barrier.
    asm volatile("s_waitcnt vmcnt(0)" ::: "memory");
    __builtin_amdgcn_sched_barrier(0);

    // ---- Q B-frags ----
    H8 qb0, qb1;
    qb0.h[0]=(_Float16)q0.x; qb0.h[1]=(_Float16)q0.y; qb0.h[2]=(_Float16)q0.z; qb0.h[3]=(_Float16)q0.w;
    qb0.h[4]=(_Float16)q1.x; qb0.h[5]=(_Float16)q1.y; qb0.h[6]=(_Float16)q1.z; qb0.h[7]=(_Float16)q1.w;
    qb1.h[0]=(_Float16)q2.x; qb1.h[1]=(_Float16)q2.y; qb1.h[2]=(_Float16)q2.z; qb1.h[3]=(_Float16)q2.w;
    qb1.h[4]=(_Float16)q3.x; qb1.h[5]=(_Float16)q3.y; qb1.h[6]=(_Float16)q3.z; qb1.h[7]=(_Float16)q3.w;

    // ---- K A-frags from LDS (swizzled reads) + QK MFMAs ----
    const int sflt = (c & 7) * 4;
    const float* krow0 = Klds + (size_t)(w * 32 + c) * 64;
    const float* krow1 = krow0 + 16 * 64;
    const float4v z4 = {0.f, 0.f, 0.f, 0.f};

    float4v kaa = *(const float4v*)&krow0[(quad * 8) ^ sflt];
    float4v kab = *(const float4v*)&krow0[(quad * 8 + 4) ^ sflt];
    float4v kac = *(const float4v*)&krow0[(32 + quad * 8) ^ sflt];
    float4v kad = *(const float4v*)&krow0[(36 + quad * 8) ^ sflt];
    H8 ka, kb;
    ka.h[0]=(_Float16)kaa[0]; ka.h[1]=(_Float16)kaa[1]; ka.h[2]=(_Float16)kaa[2]; ka.h[3]=(_Float16)kaa[3];
    ka.h[4]=(_Float16)kab[0]; ka.h[5]=(_Float16)kab[1]; ka.h[6]=(_Float16)kab[2]; ka.h[7]=(_Float16)kab[3];
    kb.h[0]=(_Float16)kac[0]; kb.h[1]=(_Float16)kac[1]; kb.h[2]=(_Float16)kac[2]; kb.h[3]=(_Float16)kac[3];
    kb.h[4]=(_Float16)kad[0]; kb.h[5]=(_Float16)kad[1]; kb.h[6]=(_Float16)kad[2]; kb.h[7]=(_Float16)kad[3];
    float4v st0 = __builtin_amdgcn_mfma_f32_16x16x32_f16(ka.v, qb0.v, z4, 0, 0, 0);
    st0 = __builtin_amdgcn_mfma_f32_16x16x32_f16(kb.v, qb1.v, st0, 0, 0, 0);

    kaa = *(const float4v*)&krow1[(quad * 8) ^ sflt];
    kab = *(const float4v*)&krow1[(quad * 8 + 4) ^ sflt];
    kac = *(const float4v*)&krow1[(32 + quad * 8) ^ sflt];
    kad = *(const float4v*)&krow1[(36 + quad * 8) ^ sflt];
    ka.h[0]=(_Float16)kaa[0]; ka.h[1]=(_Float16)kaa[1]; ka.h[2]=(_Float16)kaa[2]; ka.h[3]=(_Float16)kaa[3];
    ka.h[4]=(_Float16)kab[0]; ka.h[5]=(_Float16)kab[1]; ka.h[6]=(_Float16)kab[2]; ka.h[7]=(_Float16)kab[3];
    kb.h[0]=(_Float16)kac[0]; kb.h[1]=(_Float16)kac[1]; kb.h[2]=(_Float16)kac[2]; kb.h[3]=(_Float16)kac[3];
    kb.h[4]=(_Float16)kad[0]; kb.h[5]=(_Float16)kad[1]; kb.h[6]=(_Float16)kad[2]; kb.h[7]=(_Float16)kad[3];
    float4v st1 = __builtin_amdgcn_mfma_f32_16x16x32_f16(ka.v, qb0.v, z4, 0, 0, 0);
    st1 = __builtin_amdgcn_mfma_f32_16x16x32_f16(kb.v, qb1.v, st1, 0, 0, 0);

    // All waves' K reads retired before sacc (which aliases K) is written.
    __syncthreads();

    // ---- causal mask (per tile; only the last block's wave 3 is affected) ----
    if (tb0 + 15 > START_POS_C) {
#pragma unroll
        for (int r = 0; r < 4; ++r)
            if (tb0 + 4 * quad + r > START_POS_C + c) st0[r] = -INFINITY;
    }
    if (tb1 + 15 > START_POS_C) {
#pragma unroll
        for (int r = 0; r < 4; ++r)
            if (tb1 + 4 * quad + r > START_POS_C + c) st1[r] = -INFINITY;
    }

    // ---- single-shot softmax over this wave's 32 tokens (per query c) ----
    float tm = fmaxf(fmaxf(fmaxf(st0[0], st0[1]), fmaxf(st0[2], st0[3])),
                     fmaxf(fmaxf(st1[0], st1[1]), fmaxf(st1[2], st1[3])));
    tm = fmaxf(tm, __shfl_xor(tm, 16, 64));
    tm = fmaxf(tm, __shfl_xor(tm, 32, 64));
    H4 pa0, pa1;
    pa0.h[0]=(_Float16)exp2f(st0[0]-tm); pa0.h[1]=(_Float16)exp2f(st0[1]-tm);
    pa0.h[2]=(_Float16)exp2f(st0[2]-tm); pa0.h[3]=(_Float16)exp2f(st0[3]-tm);
    pa1.h[0]=(_Float16)exp2f(st1[0]-tm); pa1.h[1]=(_Float16)exp2f(st1[1]-tm);
    pa1.h[2]=(_Float16)exp2f(st1[2]-tm); pa1.h[3]=(_Float16)exp2f(st1[3]-tm);
    float ts = ((float)pa0.h[0] + (float)pa0.h[1]) + ((float)pa0.h[2] + (float)pa0.h[3])
             + ((float)pa1.h[0] + (float)pa1.h[1]) + ((float)pa1.h[2] + (float)pa1.h[3]);
    ts += __shfl_xor(ts, 16, 64);
    ts += __shfl_xor(ts, 32, 64);

    // ---- PV MFMAs; V B-frags gathered from LDS (2-way banks, free) ----
    const float* vrb = Vlds + (size_t)(w * 32) * 64;
    float4v acc[4];
#pragma unroll
    for (int i = 0; i < 4; ++i) acc[i] = z4;
#pragma unroll
    for (int ndv = 0; ndv < 4; ++ndv) {
        H4 bf;
#pragma unroll
        for (int j = 0; j < 4; ++j) {
            const int r = 4 * quad + j;
            const int sw = (r & 7) * 4;
            bf.h[j] = (_Float16)vrb[r * 64 + ((16 * ndv + c) ^ sw)];
        }
        acc[ndv] = __builtin_amdgcn_mfma_f32_16x16x16f16(pa0.v, bf.v, acc[ndv], 0, 0, 0);
#pragma unroll
        for (int j = 0; j < 4; ++j) {
            const int r = 4 * quad + j;
            const int sw = (r & 7) * 4;
            bf.h[j] = (_Float16)vrb[(16 + r) * 64 + ((16 * ndv + c) ^ sw)];
        }
        acc[ndv] = __builtin_amdgcn_mfma_f32_16x16x16f16(pa1.v, bf.v, acc[ndv], 0, 0, 0);
    }

    // ---- in-block merge of 4 wave-partials (sacc aliases dead K region) ----
#pragma unroll
    for (int ndv = 0; ndv < 4; ++ndv)
#pragma unroll
        for (int r = 0; r < 4; ++r)
            sacc[w][4 * quad + r][16 * ndv + c] = acc[ndv][r];
    if (quad == 0) { sm[w][c] = tm; sse[w][c] = ts; }
    __syncthreads();

    const int q = tid >> 4;
    const int dseg = tid & 15;
    float m0 = sm[0][q], m1 = sm[1][q], m2 = sm[2][q], m3 = sm[3][q];
    float M = fmaxf(fmaxf(m0, m1), fmaxf(m2, m3));
    float u0 = exp2f(m0 - M), u1 = exp2f(m1 - M), u2 = exp2f(m2 - M), u3 = exp2f(m3 - M);
    float den = u0 * sse[0][q] + u1 * sse[1][q] + u2 * sse[2][q] + u3 * sse[3][q];
    float4v num = u0 * (*(const float4v*)&sacc[0][q][4 * dseg])
                + u1 * (*(const float4v*)&sacc[1][q][4 * dseg])
                + u2 * (*(const float4v*)&sacc[2][q][4 * dseg])
                + u3 * (*(const float4v*)&sacc[3][q][4 * dseg]);
    const size_t ob = ((size_t)(h * SPLITS + s) * L_TOK + q) * DHEAD + 4 * dseg;
    *(float4v*)&accws[ob] = num;
    if (dseg == 0) {
        const size_t mb = (size_t)(h * SPLITS + s) * L_TOK + q;
        m_arr[mb] = M;
        se_arr[mb] = den;
    }
}

// ---------------------------------------------------------------------------
// Combine split partials (two-pass, independent loads — unchanged).
// ---------------------------------------------------------------------------
__global__ __launch_bounds__(256) void combine(const float* __restrict__ accws,
                                               const float* __restrict__ m_arr,
                                               const float* __restrict__ se_arr,
                                               float* __restrict__ attnws) {
    const int h = blockIdx.x >> 4;
    const int l = blockIdx.x & 15;
    const int w = threadIdx.x >> 6;
    const int lane = threadIdx.x & 63;
    __shared__ float sm[4], sse[4], sacc[4][64];

    const size_t base = (size_t)h * SPLITS * L_TOK + l;

    float mreg[SPLITS / 4];
#pragma unroll
    for (int i = 0; i < SPLITS / 4; ++i)
        mreg[i] = m_arr[base + (size_t)(w + 4 * i) * L_TOK];
    float M = -INFINITY;
#pragma unroll
    for (int i = 0; i < SPLITS / 4; ++i) M = fmaxf(M, mreg[i]);

    float num = 0.f, den = 0.f;
#pragma unroll
    for (int i = 0; i < SPLITS / 4; ++i) {
        const size_t idx = base + (size_t)(w + 4 * i) * L_TOK;
        const float wgt = exp2f(mreg[i] - M);
        num = fmaf(wgt, accws[idx * DHEAD + lane], num);
        den = fmaf(wgt, se_arr[idx], den);
    }

    if (lane == 0) { sm[w] = M; sse[w] = den; }
    sacc[w][lane] = num;
    __syncthreads();
    if (w == 0) {
        const float M0 = fmaxf(fmaxf(sm[0], sm[1]), fmaxf(sm[2], sm[3]));
        float nn = 0.f, dd = 0.f;
#pragma unroll
        for (int i = 0; i < 4; ++i) {
            const float wgt = exp2f(sm[i] - M0);
            nn = fmaf(wgt, sacc[i][lane], nn);
            dd = fmaf(wgt, sse[i], dd);
        }
        attnws[(size_t)l * DMODEL + h * DHEAD + lane] = nn / dd;
    }
}

// ---------------------------------------------------------------------------
// Reduce split-K partials of final projection + bias -> d_out. v2: array
// loads + tree sum (independent loads).
// ---------------------------------------------------------------------------
__global__ __launch_bounds__(256) void proj_reduce(const float* __restrict__ part,
                                                   const float* __restrict__ bias,
                                                   float* __restrict__ out) {
    int tid = blockIdx.x * 256 + threadIdx.x;   // < 16384
    int n = tid & (DMODEL - 1);
    int l = tid >> 10;
    float p[KSPLIT];
#pragma unroll
    for (int kb = 0; kb < KSPLIT; ++kb)
        p[kb] = part[((size_t)kb * L_TOK + l) * DMODEL + n];
#pragma unroll
    for (int st = 1; st < KSPLIT; st <<= 1)
#pragma unroll
        for (int i = 0; i < KSPLIT; i += 2 * st) p[i] += p[i + st];
    out[tid] = bias[n] + p[0];
}

extern "C" void kernel_launch(void* const* d_in, const int* in_sizes, int n_in,
                              void* d_out, int out_size, void* d_ws, size_t ws_size,
                              hipStream_t stream) {
    const float* x       = (const float*)d_in[0];
    float* kpool         = (float*)d_in[1];
    float* vpool         = (float*)d_in[2];
    const float* W_attn  = (const float*)d_in[3];
    const float* b_attn  = (const float*)d_in[4];
    const float* W_proj  = (const float*)d_in[5];
    const float* b_proj  = (const float*)d_in[6];
    const int* block_ids = (const int*)d_in[7];
    float* ws  = (float*)d_ws;
    float* out = (float*)d_out;

    // 1) QKV projection (split-K partials)
    gemm_part<<<dim3(12, KSPLIT), 256, 0, stream>>>(x, W_attn, ws + OFF_QKVP, 3 * DMODEL);
    // 2) reduce + bias; q -> ws (scaled), new k/v -> pools (paged write)
    qkv_reduce_scatter<<<192, 256, 0, stream>>>(ws + OFF_QKVP, b_attn, block_ids,
                                                ws + OFF_QW, kpool, vpool);
    // 3) flash-decode attention (LDS-DMA staged K/V)
    paged_attn<<<dim3(NHEAD, SPLITS), 256, 0, stream>>>(kpool, vpool, block_ids,
                                                        ws + OFF_QW, ws + OFF_ACC,
                                                        ws + OFF_M, ws + OFF_SE);
    // 4) combine splits
    combine<<<NHEAD * L_TOK, 256, 0, stream>>>(ws + OFF_ACC, ws + OFF_M, ws + OFF_SE,
                                               ws + OFF_ATTN);
    // 5) output projection (split-K partials)
    gemm_part<<<dim3(4, KSPLIT), 256, 0, stream>>>(ws + OFF_ATTN, W_proj, ws + OFF_PROJP, DMODEL);
    // 6) reduce + bias -> d_out
    proj_reduce<<<64, 256, 0, stream>>>(ws + OFF_PROJP, b_proj, out);
}